// Round 12
// baseline (638.626 us; speedup 1.0000x reference)
//
#include <hip/hip_runtime.h>
#include <hip/hip_bf16.h>
#include <math.h>

// Problem constants
#define NB   8
#define NT   1024
#define NG   128
#define NS   1152      // NT + NG
#define NDIN 512
#define NDM  512
#define NH   8
#define NDH  64
#define NFF  2048
#define NL   2

typedef __attribute__((ext_vector_type(4))) float  floatx4;
typedef __attribute__((ext_vector_type(8))) short  shortx8;

__device__ __forceinline__ float gelu_f(float x) {
    float u = 1.5957691216057308f * (x + 0.044715f * x * x * x);
    return x / (1.0f + __expf(-u));
}

__device__ __forceinline__ void gload_lds16(const void* g, void* l) {
    __builtin_amdgcn_global_load_lds((const __attribute__((address_space(1))) unsigned int*)g,
                                     (__attribute__((address_space(3))) unsigned int*)l, 16, 0, 0);
}

__device__ __forceinline__ short f2bfs(float x) {
    __hip_bfloat16 h = __float2bfloat16(x);
    return *(short*)&h;
}
// truncating (RTZ) pack of two fp32 -> bf16x2; cheap, used only for P
__device__ __forceinline__ unsigned pack_bf2_rz(float a, float b) {
    unsigned au = *(unsigned*)&a, bu = *(unsigned*)&b;
    return (au >> 16) | (bu & 0xFFFF0000u);
}

// ---------------- merged prep: rope table + feature transpose + all weight transposes ----------------
__device__ __forceinline__ void wtile(const float* __restrict__ src,
        __hip_bfloat16* __restrict__ dst, int K, int N, int i, int tid, short tile[32][33])
{
    const int gx = N / 32;
    const int n0 = (i % gx) * 32;
    const int k0 = (i / gx) * 32;
    {
        const int r = tid >> 3, c4 = (tid & 7) * 4;
        float4 v = *(const float4*)&src[(size_t)(k0 + r) * N + n0 + c4];
        tile[c4 + 0][r] = f2bfs(v.x);
        tile[c4 + 1][r] = f2bfs(v.y);
        tile[c4 + 2][r] = f2bfs(v.z);
        tile[c4 + 3][r] = f2bfs(v.w);
    }
    __syncthreads();
    {
        const int r = tid >> 3, c4 = (tid & 7) * 4;
        short* dp = (short*)dst + (size_t)(n0 + r) * K + k0 + c4;
        short4 v;
        v.x = tile[r][c4 + 0]; v.y = tile[r][c4 + 1];
        v.z = tile[r][c4 + 2]; v.w = tile[r][c4 + 3];
        *(short4*)dp = v;
    }
}

__global__ __launch_bounds__(256) void prep0_k(
        float2* __restrict__ tab,
        const float* __restrict__ features, float* __restrict__ featT,
        const float* W_in, const float* Wq, const float* Wk, const float* Wv,
        const float* Wo, const float* W1, const float* W2, const float* W_out,
        __hip_bfloat16* w_inT, __hip_bfloat16* wqkvT0, __hip_bfloat16* wqkvT1,
        __hip_bfloat16* woT0, __hip_bfloat16* woT1,
        __hip_bfloat16* w1T0, __hip_bfloat16* w1T1,
        __hip_bfloat16* w2T0, __hip_bfloat16* w2T1, __hip_bfloat16* woutT)
{
    __shared__ __align__(16) char smem[32 * 33 * 4];
    const int tid = threadIdx.x;
    const int blk = blockIdx.x;
    if (blk < 144) {
        const int idx = blk * 256 + tid;     // < 36864 = NS*32
        const int s = idx >> 5, i = idx & 31;
        const float fr = __expf(-(float)i * 0.28782313662425576f);
        const float ang = (float)s * fr;
        tab[idx] = make_float2(cosf(ang), sinf(ang));
    } else if (blk < 144 + 4096) {
        float (*tile)[33] = (float(*)[33])smem;
        const int v = blk - 144;
        const int t0 = (v & 31) * 32;
        const int d0 = ((v >> 5) & 15) * 32;
        const int b  = v >> 9;
        const int r = tid >> 3, c4 = (tid & 7) * 4;
        {
            float4 w = *(const float4*)&features[((size_t)(b * NDIN + d0 + r)) * NT + t0 + c4];
            tile[c4 + 0][r] = w.x; tile[c4 + 1][r] = w.y;
            tile[c4 + 2][r] = w.z; tile[c4 + 3][r] = w.w;
        }
        __syncthreads();
        {
            float4 w;
            w.x = tile[r][c4 + 0]; w.y = tile[r][c4 + 1];
            w.z = tile[r][c4 + 2]; w.w = tile[r][c4 + 3];
            *(float4*)&featT[((size_t)(b * NT + t0 + r)) * NDIN + d0 + c4] = w;
        }
    } else {
        short (*tile)[33] = (short(*)[33])smem;
        const int i = blk - (144 + 4096);    // < 6656
        const float* src; __hip_bfloat16* dst; int K, N, ti;
        if (i < 256) { src = W_in; dst = w_inT; K = 512; N = 512; ti = i; }
        else if (i < 6400) {
            int r = i - 256;
            const int l = r / 3072; r -= l * 3072;
            const size_t o5 = (size_t)l * 262144, o2 = (size_t)l * 1048576;
            if (r < 256)       { src = Wq + o5; dst = (l ? wqkvT1 : wqkvT0);          K = 512;  N = 512;  ti = r; }
            else if (r < 512)  { src = Wk + o5; dst = (l ? wqkvT1 : wqkvT0) + 262144; K = 512;  N = 512;  ti = r - 256; }
            else if (r < 768)  { src = Wv + o5; dst = (l ? wqkvT1 : wqkvT0) + 524288; K = 512;  N = 512;  ti = r - 512; }
            else if (r < 1024) { src = Wo + o5; dst = (l ? woT1 : woT0);              K = 512;  N = 512;  ti = r - 768; }
            else if (r < 2048) { src = W1 + o2; dst = (l ? w1T1 : w1T0);              K = 512;  N = 2048; ti = r - 1024; }
            else               { src = W2 + o2; dst = (l ? w2T1 : w2T0);              K = 2048; N = 512;  ti = r - 2048; }
        }
        else { src = W_out; dst = woutT; K = 512; N = 512; ti = i - 6400; }
        wtile(src, dst, K, N, ti, tid, tile);
    }
}

// ---------------- merged group-pool: stats + mean-pooled queries (featT, coalesced) ----------------
__global__ __launch_bounds__(256) void pool_k(const float* __restrict__ align,
        const float* __restrict__ featT, int* __restrict__ glast,
        float* __restrict__ queries)
{
    __shared__ float redf[256];
    __shared__ int   redi[256];
    __shared__ float aw[NT];
    const int bg = blockIdx.x;           // b*NG + g
    const int b = bg >> 7;
    const int tid = threadIdx.x;
    const float* arow = align + (size_t)bg * NT;
    float cnt = 0.f, last = 0.f;
    int tmin = NT;
    for (int t = tid; t < NT; t += 256) {
        float a = arow[t];
        cnt += a;
        last = fmaxf(last, a * (float)t);
        if (a > 0.f) tmin = min(tmin, t);
    }
    redf[tid] = cnt; __syncthreads();
    for (int s = 128; s > 0; s >>= 1) { if (tid < s) redf[tid] += redf[tid + s]; __syncthreads(); }
    float c = redf[0]; __syncthreads();
    redf[tid] = last; __syncthreads();
    for (int s = 128; s > 0; s >>= 1) { if (tid < s) redf[tid] = fmaxf(redf[tid], redf[tid + s]); __syncthreads(); }
    float l = redf[0];
    redi[tid] = tmin; __syncthreads();
    for (int s = 128; s > 0; s >>= 1) { if (tid < s) redi[tid] = min(redi[tid], redi[tid + s]); __syncthreads(); }
    const int t0 = redi[0];
    const int t1 = (int)l;
    if (tid == 0) glast[bg] = t1;
    __syncthreads();
    for (int t = t0 + tid; t <= t1; t += 256) aw[t - t0] = arow[t];
    __syncthreads();
    const float invc = 1.0f / fmaxf(c, 1.0f);
    const float* fT = featT + (size_t)b * NT * NDIN;
    for (int d = tid; d < NDIN; d += 256) {
        float s = 0.f;
        for (int t = t0; t <= t1; ++t) s += aw[t - t0] * fT[(size_t)t * NDIN + d];
        queries[(size_t)bg * NDIN + d] = s * invc;
    }
}

// ---------------- stable-argsort rank ----------------
__global__ __launch_bounds__(256) void rank_k(const int* __restrict__ glast,
        const int* __restrict__ nsegp, int* __restrict__ perm, int* __restrict__ qpos)
{
    __shared__ int dm[NS];
    __shared__ int gl[NG];
    const int b = blockIdx.y;
    const int tid = threadIdx.x;
    const int j = blockIdx.x * 256 + tid;
    if (tid < NG) gl[tid] = glast[b * NG + tid];
    const int ns = nsegp[b];
    __syncthreads();
    for (int jj = tid; jj < NS; jj += 256) {
        int d;
        if (jj < NT) {
            int t = jj, nq = 0, flen = 0;
            for (int g = 0; g < ns; ++g) {
                flen = max(flen, gl[g] + 1);
                nq += (gl[g] < t) ? 1 : 0;
            }
            d = (t < flen) ? (t + nq) : NS;
        } else {
            int g = jj - NT;
            d = (g < ns) ? (gl[g] + g + 1) : NS;
        }
        dm[jj] = d;
    }
    __syncthreads();
    if (j < NS) {
        const int my = dm[j];
        int r = 0;
        for (int t = 0; t < NS; ++t) {
            int v2 = dm[t];
            r += (v2 < my || (v2 == my && t < j)) ? 1 : 0;
        }
        perm[b * NS + r] = j;
        if (j >= NT) qpos[b * NG + (j - NT)] = r;
    }
}

// ---------------- build transformer input X (bf16, float4-vectorized, coalesced) ----------------
__global__ __launch_bounds__(256) void buildx_k(const float* __restrict__ featT,
        const float* __restrict__ queries, const int* __restrict__ perm,
        __hip_bfloat16* __restrict__ X)
{
    const int idx = blockIdx.x * 256 + threadIdx.x;    // NB*NS*(NDIN/4)
    if (idx >= NB * NS * (NDIN / 4)) return;
    const int dq = idx & 127;
    const int p = (idx >> 7) % NS;
    const int b = idx / (NS * 128);
    const int j = perm[b * NS + p];
    const float4* src = (j < NT)
        ? (const float4*)&featT[((size_t)(b * NT + j)) * NDIN]
        : (const float4*)&queries[((size_t)(b * NG + (j - NT))) * NDIN];
    float4 v = src[dq];
    short4 o;
    o.x = f2bfs(v.x); o.y = f2bfs(v.y); o.z = f2bfs(v.z); o.w = f2bfs(v.w);
    *(short4*)((short*)X + ((size_t)(b * NS + p)) * NDIN + dq * 4) = o;
}

// ---------------- W1 GEMM: 128x128, double-stage BK=64, gelu, LDS-coalesced bf16 out ----------------
__global__ __launch_bounds__(256) void bgemmw1_k(const __hip_bfloat16* __restrict__ A,
        const __hip_bfloat16* __restrict__ Bt, __hip_bfloat16* __restrict__ Cout,
        const float* __restrict__ bias, int M, int N, int K)
{
    __shared__ __align__(16) short SM[4][128 * 32];
    short* As0 = SM[0]; short* As1 = SM[1];
    short* Bs0 = SM[2]; short* Bs1 = SM[3];
    const int tid = threadIdx.x;
    const int wave = tid >> 6, lane = tid & 63;
    const int quad = lane >> 4, l16 = lane & 15;
    const int wm = wave >> 1, wn = wave & 1;
    const size_t bm = (size_t)blockIdx.y * 128, bn = (size_t)blockIdx.x * 128;
    const int sw = (l16 >> 1) & 3;
    const short* Ag = (const short*)A;
    const short* Bg = (const short*)Bt;
    const int lrow = lane >> 2;
    const int lchunk = (lane & 3) ^ ((lane >> 3) & 3);

    floatx4 acc[4][4];
#pragma unroll
    for (int i = 0; i < 4; ++i)
#pragma unroll
        for (int j = 0; j < 4; ++j) acc[i][j] = (floatx4){0.f, 0.f, 0.f, 0.f};

    for (int k0 = 0; k0 < K; k0 += 64) {
        __syncthreads();
#pragma unroll
        for (int c = 0; c < 2; ++c) {
            const int r0 = (c * 4 + wave) * 16;
            const size_t ra = (bm + r0 + lrow) * (size_t)K + k0 + lchunk * 8;
            const size_t rb = (bn + r0 + lrow) * (size_t)K + k0 + lchunk * 8;
            gload_lds16(Ag + ra,      &As0[r0 * 32]);
            gload_lds16(Ag + ra + 32, &As1[r0 * 32]);
            gload_lds16(Bg + rb,      &Bs0[r0 * 32]);
            gload_lds16(Bg + rb + 32, &Bs1[r0 * 32]);
        }
        __syncthreads();
#pragma unroll
        for (int h = 0; h < 2; ++h) {
            const short* Asrc = h ? As1 : As0;
            const short* Bsrc = h ? Bs1 : Bs0;
            shortx8 af[4], bf[4];
#pragma unroll
            for (int t = 0; t < 4; ++t) {
                af[t] = *(const shortx8*)&Asrc[(wm * 64 + t * 16 + l16) * 32 + ((quad ^ sw) * 8)];
                bf[t] = *(const shortx8*)&Bsrc[(wn * 64 + t * 16 + l16) * 32 + ((quad ^ sw) * 8)];
            }
#pragma unroll
            for (int mt = 0; mt < 4; ++mt)
#pragma unroll
                for (int nt = 0; nt < 4; ++nt)
                    acc[mt][nt] = __builtin_amdgcn_mfma_f32_16x16x32_bf16(af[mt], bf[nt], acc[mt][nt], 0, 0, 0);
        }
    }
    __syncthreads();
    const size_t mbase = bm + wm * 64;
    const size_t nbase = bn + wn * 64;
    short* ep = &SM[wave][0];
#pragma unroll
    for (int nt = 0; nt < 4; ++nt) {
        const size_t n = nbase + nt * 16 + l16;
        const float bz = bias[n];
        const int col = nt * 16 + l16;
#pragma unroll
        for (int mt = 0; mt < 4; ++mt)
#pragma unroll
            for (int r = 0; r < 4; ++r) {
                const int rl = mt * 16 + quad * 4 + r;
                float e = gelu_f(acc[mt][nt][r] + bz);
                ep[rl * 64 + (((col >> 3) ^ (rl & 7)) * 8) + (col & 7)] = f2bfs(e);
            }
    }
    __asm__ __volatile__("" ::: "memory");
#pragma unroll
    for (int c2 = 0; c2 < 8; ++c2) {
        const int rl = c2 * 8 + (lane >> 3);
        const int cc = lane & 7;
        shortx8 v = *(const shortx8*)&ep[rl * 64 + ((cc ^ (rl & 7)) * 8)];
        *(shortx8*)((short*)Cout + (mbase + rl) * N + nbase + cc * 8) = v;
    }
}

// ---------------- QKV GEMM: fused RoPE + head-major + V-transpose, LDS-coalesced stores ----------
__global__ __launch_bounds__(256) void bgemmqkv_k(const __hip_bfloat16* __restrict__ A,
        const __hip_bfloat16* __restrict__ Bt, __hip_bfloat16* __restrict__ qh,
        __hip_bfloat16* __restrict__ kh, __hip_bfloat16* __restrict__ vT,
        const float2* __restrict__ tab)
{
    __shared__ __align__(16) short SM[4][128 * 32];
    short* As0 = SM[0]; short* As1 = SM[1];
    short* Bs0 = SM[2]; short* Bs1 = SM[3];
    const int tid = threadIdx.x;
    const int wave = tid >> 6, lane = tid & 63;
    const int quad = lane >> 4, l16 = lane & 15;
    const int wm = wave >> 1, wn = wave & 1;
    const size_t bm = (size_t)blockIdx.y * 128, bn = (size_t)blockIdx.x * 128;
    const int sw = (l16 >> 1) & 3;
    const int K = 512;
    const short* Ag = (const short*)A;
    const short* Bg = (const short*)Bt;
    const int lrow = lane >> 2;
    const int lchunk = (lane & 3) ^ ((lane >> 3) & 3);

    floatx4 acc[4][4];
#pragma unroll
    for (int i = 0; i < 4; ++i)
#pragma unroll
        for (int j = 0; j < 4; ++j) acc[i][j] = (floatx4){0.f, 0.f, 0.f, 0.f};

    for (int k0 = 0; k0 < K; k0 += 64) {
        __syncthreads();
#pragma unroll
        for (int c = 0; c < 2; ++c) {
            const int r0 = (c * 4 + wave) * 16;
            const size_t ra = (bm + r0 + lrow) * (size_t)K + k0 + lchunk * 8;
            const size_t rb = (bn + r0 + lrow) * (size_t)K + k0 + lchunk * 8;
            gload_lds16(Ag + ra,      &As0[r0 * 32]);
            gload_lds16(Ag + ra + 32, &As1[r0 * 32]);
            gload_lds16(Bg + rb,      &Bs0[r0 * 32]);
            gload_lds16(Bg + rb + 32, &Bs1[r0 * 32]);
        }
        __syncthreads();
#pragma unroll
        for (int h = 0; h < 2; ++h) {
            const short* Asrc = h ? As1 : As0;
            const short* Bsrc = h ? Bs1 : Bs0;
            shortx8 af[4], bf[4];
#pragma unroll
            for (int t = 0; t < 4; ++t) {
                af[t] = *(const shortx8*)&Asrc[(wm * 64 + t * 16 + l16) * 32 + ((quad ^ sw) * 8)];
                bf[t] = *(const shortx8*)&Bsrc[(wn * 64 + t * 16 + l16) * 32 + ((quad ^ sw) * 8)];
            }
#pragma unroll
            for (int mt = 0; mt < 4; ++mt)
#pragma unroll
                for (int nt = 0; nt < 4; ++nt)
                    acc[mt][nt] = __builtin_amdgcn_mfma_f32_16x16x32_bf16(af[mt], bf[nt], acc[mt][nt], 0, 0, 0);
        }
    }
    __syncthreads();
    short* ep = &SM[wave][0];
    const int bidx = (int)(bm / NS);
    const int sbase = (int)(bm - (size_t)bidx * NS) + wm * 64;
    const int region = (int)(bn >> 9);     // 0=q, 1=k, 2=v
    if (region < 2) {
        const float qsc = region ? 1.0f : 0.18033688011112043f;  // 0.125 * log2(e)
        const int h = (int)((((int)bn & 511) + wn * 64) >> 6);
#pragma unroll
        for (int nt = 0; nt < 2; ++nt) {
            const int d1 = nt * 16 + l16, d2 = d1 + 32;
            const float2* tp = tab + d1;
#pragma unroll
            for (int mt = 0; mt < 4; ++mt)
#pragma unroll
                for (int r = 0; r < 4; ++r) {
                    const int sl = mt * 16 + quad * 4 + r;
                    const int s = sbase + sl;
                    float x1 = acc[mt][nt][r], x2 = acc[mt][nt + 2][r];
                    float2 cs = tp[s * 32];
                    ep[sl * 64 + (((d1 >> 3) ^ (sl & 7)) * 8) + (d1 & 7)] = f2bfs(qsc * (x1 * cs.x - x2 * cs.y));
                    ep[sl * 64 + (((d2 >> 3) ^ (sl & 7)) * 8) + (d2 & 7)] = f2bfs(qsc * (x1 * cs.y + x2 * cs.x));
                }
        }
        __asm__ __volatile__("" ::: "memory");
        short* dst = (short*)(region ? kh : qh) + ((size_t)(bidx * NH + h)) * NS * NDH;
#pragma unroll
        for (int c2 = 0; c2 < 8; ++c2) {
            const int sl = c2 * 8 + (lane >> 3);
            const int cc = lane & 7;
            shortx8 v = *(const shortx8*)&ep[sl * 64 + ((cc ^ (sl & 7)) * 8)];
            *(shortx8*)(dst + (size_t)(sbase + sl) * NDH + cc * 8) = v;
        }
    } else {
        const int base = (int)(bn - 1024) + wn * 64;
        const int h = base >> 6;
#pragma unroll
        for (int nt = 0; nt < 4; ++nt) {
            const int dl = nt * 16 + l16;
#pragma unroll
            for (int mt = 0; mt < 4; ++mt)
#pragma unroll
                for (int r = 0; r < 4; ++r) {
                    const int sl = mt * 16 + quad * 4 + r;
                    ep[dl * 64 + (((sl >> 3) ^ (dl & 7)) * 8) + (sl & 7)] = f2bfs(acc[mt][nt][r]);
                }
        }
        __asm__ __volatile__("" ::: "memory");
        short* vp = (short*)vT + ((size_t)(bidx * NH + h)) * NDH * NS;
#pragma unroll
        for (int c2 = 0; c2 < 8; ++c2) {
            const int dl = c2 * 8 + (lane >> 3);
            const int cc = lane & 7;
            shortx8 v = *(const shortx8*)&ep[dl * 64 + ((cc ^ (dl & 7)) * 8)];
            *(shortx8*)(vp + (size_t)dl * NS + sbase + cc * 8) = v;
        }
    }
}

// ---------------- bf16 MFMA GEMM 64x128 tile, double-stage BK=64 (N=512 shapes) ----------------
// EPI 0: acc+bias?  EPI 2: res + ls*(acc+bias?)  EPI 4: masked transposed writeout (W_out)
template <int EPI>
__global__ __launch_bounds__(256) void bgemm64_k(const __hip_bfloat16* __restrict__ A,
        const __hip_bfloat16* __restrict__ Bt, void* __restrict__ Cout,
        const float* __restrict__ bias, const float* __restrict__ ls,
        const float* __restrict__ res, const int* __restrict__ nsegp, int M, int N, int K)
{
    __shared__ __align__(16) short As0[64 * 32], As1[64 * 32];
    __shared__ __align__(16) short Bs0[128 * 32], Bs1[128 * 32];
    const int tid = threadIdx.x;
    const int wave = tid >> 6, lane = tid & 63;
    const int quad = lane >> 4, l16 = lane & 15;
    const int wm = wave >> 1, wn = wave & 1;
    const size_t bm = (size_t)blockIdx.y * 64, bn = (size_t)blockIdx.x * 128;
    const int sw = (l16 >> 1) & 3;
    const short* Ag = (const short*)A;
    const short* Bg = (const short*)Bt;
    const int lrow = lane >> 2;
    const int lchunk = (lane & 3) ^ ((lane >> 3) & 3);

    floatx4 acc[2][4];
#pragma unroll
    for (int i = 0; i < 2; ++i)
#pragma unroll
        for (int j = 0; j < 4; ++j) acc[i][j] = (floatx4){0.f, 0.f, 0.f, 0.f};

    for (int k0 = 0; k0 < K; k0 += 64) {
        __syncthreads();
        {
            const int rA = wave * 16;
            const size_t ra = (bm + rA + lrow) * (size_t)K + k0 + lchunk * 8;
            gload_lds16(Ag + ra,      &As0[rA * 32]);
            gload_lds16(Ag + ra + 32, &As1[rA * 32]);
            const int rB = wave * 32;
            const size_t rb0 = (bn + rB + lrow) * (size_t)K + k0 + lchunk * 8;
            const size_t rb1 = (bn + rB + 16 + lrow) * (size_t)K + k0 + lchunk * 8;
            gload_lds16(Bg + rb0,      &Bs0[rB * 32]);
            gload_lds16(Bg + rb1,      &Bs0[(rB + 16) * 32]);
            gload_lds16(Bg + rb0 + 32, &Bs1[rB * 32]);
            gload_lds16(Bg + rb1 + 32, &Bs1[(rB + 16) * 32]);
        }
        __syncthreads();
#pragma unroll
        for (int h = 0; h < 2; ++h) {
            const short* Asrc = h ? As1 : As0;
            const short* Bsrc = h ? Bs1 : Bs0;
            shortx8 af[2], bf[4];
#pragma unroll
            for (int t = 0; t < 2; ++t)
                af[t] = *(const shortx8*)&Asrc[(wm * 32 + t * 16 + l16) * 32 + ((quad ^ sw) * 8)];
#pragma unroll
            for (int t = 0; t < 4; ++t)
                bf[t] = *(const shortx8*)&Bsrc[(wn * 64 + t * 16 + l16) * 32 + ((quad ^ sw) * 8)];
#pragma unroll
            for (int mt = 0; mt < 2; ++mt)
#pragma unroll
                for (int nt = 0; nt < 4; ++nt)
                    acc[mt][nt] = __builtin_amdgcn_mfma_f32_16x16x32_bf16(af[mt], bf[nt], acc[mt][nt], 0, 0, 0);
        }
    }
    const size_t mbase = bm + wm * 32;
    const size_t nbase = bn + wn * 64;
#pragma unroll
    for (int nt = 0; nt < 4; ++nt) {
        const size_t n = nbase + nt * 16 + l16;
        const float bz = bias ? bias[n] : 0.f;
        const float lz = (EPI == 2) ? ls[n] : 0.f;
#pragma unroll
        for (int mt = 0; mt < 2; ++mt) {
#pragma unroll
            for (int r = 0; r < 4; ++r) {
                const size_t m = mbase + mt * 16 + quad * 4 + r;
                float e = acc[mt][nt][r] + bz;
                if (EPI == 4) {
                    const int b = (int)(m >> 7), g = (int)(m & 127);
                    float val = (g < nsegp[b]) ? e : 0.0f;
                    ((float*)Cout)[(size_t)b * (NDIN * NG) + n * NG + g] = val;
                } else {
                    const size_t off = m * N + n;
                    if (EPI == 2) e = res[off] + lz * e;
                    ((float*)Cout)[off] = e;
                }
            }
        }
    }
}

// ---------------- wave-per-row LayerNorm, 4 rows/block (fp32 in -> bf16 out) ----------------
__global__ __launch_bounds__(256) void lnw_k(const float* __restrict__ in,
        __hip_bfloat16* __restrict__ out, const float* __restrict__ gam, const float* __restrict__ bet)
{
    const int r = blockIdx.x * 4 + (threadIdx.x >> 6);
    const int t = threadIdx.x & 63;
    const float4* xp = (const float4*)(in + (size_t)r * NDM);
    float4 a = xp[t * 2], b4 = xp[t * 2 + 1];
    float s = a.x + a.y + a.z + a.w + b4.x + b4.y + b4.z + b4.w;
#pragma unroll
    for (int o = 1; o < 64; o <<= 1) s += __shfl_xor(s, o);
    const float mean = s * (1.0f / NDM);
    float dx[8] = {a.x - mean, a.y - mean, a.z - mean, a.w - mean,
                   b4.x - mean, b4.y - mean, b4.z - mean, b4.w - mean};
    float v = 0.f;
#pragma unroll
    for (int i = 0; i < 8; ++i) v += dx[i] * dx[i];
#pragma unroll
    for (int o = 1; o < 64; o <<= 1) v += __shfl_xor(v, o);
    const float inv = rsqrtf(v * (1.0f / NDM) + 1e-5f);
    const float4* gp = (const float4*)gam;
    const float4* bp = (const float4*)bet;
    float4 g0 = gp[t * 2], g1 = gp[t * 2 + 1], q0 = bp[t * 2], q1 = bp[t * 2 + 1];
    shortx8 o8;
    o8[0] = f2bfs(dx[0] * inv * g0.x + q0.x);
    o8[1] = f2bfs(dx[1] * inv * g0.y + q0.y);
    o8[2] = f2bfs(dx[2] * inv * g0.z + q0.z);
    o8[3] = f2bfs(dx[3] * inv * g0.w + q0.w);
    o8[4] = f2bfs(dx[4] * inv * g1.x + q1.x);
    o8[5] = f2bfs(dx[5] * inv * g1.y + q1.y);
    o8[6] = f2bfs(dx[6] * inv * g1.z + q1.z);
    o8[7] = f2bfs(dx[7] * inv * g1.w + q1.w);
    *(shortx8*)((short*)out + (size_t)r * NDM + t * 8) = o8;
}

// ---------------- wave-per-row final LN over gathered query rows ----------------
__global__ __launch_bounds__(64) void lnwg_k(const float* __restrict__ h,
        __hip_bfloat16* __restrict__ out, const float* __restrict__ gam, const float* __restrict__ bet,
        const int* __restrict__ qpos)
{
    const int r = blockIdx.x, t = threadIdx.x;   // r = b*NG + g
    const int b = r >> 7;
    const int src = qpos[r];
    const float4* xp = (const float4*)(h + ((size_t)(b * NS + src)) * NDM);
    float4 a = xp[t * 2], b4 = xp[t * 2 + 1];
    float s = a.x + a.y + a.z + a.w + b4.x + b4.y + b4.z + b4.w;
#pragma unroll
    for (int o = 1; o < 64; o <<= 1) s += __shfl_xor(s, o);
    const float mean = s * (1.0f / NDM);
    float dx[8] = {a.x - mean, a.y - mean, a.z - mean, a.w - mean,
                   b4.x - mean, b4.y - mean, b4.z - mean, b4.w - mean};
    float v = 0.f;
#pragma unroll
    for (int i = 0; i < 8; ++i) v += dx[i] * dx[i];
#pragma unroll
    for (int o = 1; o < 64; o <<= 1) v += __shfl_xor(v, o);
    const float inv = rsqrtf(v * (1.0f / NDM) + 1e-5f);
    const float4* gp = (const float4*)gam;
    const float4* bp = (const float4*)bet;
    float4 g0 = gp[t * 2], g1 = gp[t * 2 + 1], q0 = bp[t * 2], q1 = bp[t * 2 + 1];
    shortx8 o8;
    o8[0] = f2bfs(dx[0] * inv * g0.x + q0.x);
    o8[1] = f2bfs(dx[1] * inv * g0.y + q0.y);
    o8[2] = f2bfs(dx[2] * inv * g0.z + q0.z);
    o8[3] = f2bfs(dx[3] * inv * g0.w + q0.w);
    o8[4] = f2bfs(dx[4] * inv * g1.x + q1.x);
    o8[5] = f2bfs(dx[5] * inv * g1.y + q1.y);
    o8[6] = f2bfs(dx[6] * inv * g1.z + q1.z);
    o8[7] = f2bfs(dx[7] * inv * g1.w + q1.w);
    *(shortx8*)((short*)out + (size_t)r * NDM + t * 8) = o8;
}

// ---------------- flash attention v9: 128-query block, shared K/V fragment reads ----------------
#define FKT 64
#define FKP 68
#define NTL (NS / FKT)   // 18
__global__ __launch_bounds__(256) void fattn_k(const __hip_bfloat16* __restrict__ qb,
        const __hip_bfloat16* __restrict__ kb, const __hip_bfloat16* __restrict__ vbT,
        __hip_bfloat16* __restrict__ o)
{
    __shared__ __align__(16) short Ks[FKT * FKP];          // 8.7 KB [key][d]
    __shared__ __align__(16) short Vt[(NDH + 16) * FKP];   // 10.9 KB [d][key], rows 64..79 = ones
    __shared__ __align__(16) short Pl[128 * FKP];          // 17.4 KB [local q][key]
    const int tid = threadIdx.x;
    const int wave = tid >> 6, lane = tid & 63;
    const int quad = lane >> 4, l16 = lane & 15;
    const int L = blockIdx.x;                   // 576 = 8 xcd * (8 bh-low * 9 qtiles)
    const int xcd = L & 7, sl = L >> 3;
    const int bh = (xcd << 3) | (sl & 7);
    const int q0 = (sl >> 3) * 128;
    const int bb = bh >> 3, hh = bh & 7;
    const short* qbase = (const short*)qb + (size_t)bh * NS * NDH;
    const short* kbase = (const short*)kb + (size_t)bh * NS * NDH;
    const short* vbase = (const short*)vbT + (size_t)bh * NDH * NS;

    // two Q-fragment sets per wave: rows wave*32 + (0..15) and + (16..31)
    shortx8 QfA0, QfA1, QfB0, QfB1;
    {
        const short* qpA = qbase + (size_t)(q0 + wave * 32 + l16) * NDH + quad * 8;
        QfA0 = *(const shortx8*)qpA;
        QfA1 = *(const shortx8*)(qpA + 32);
        const short* qpB = qpA + 16 * NDH;
        QfB0 = *(const shortx8*)qpB;
        QfB1 = *(const shortx8*)(qpB + 32);
    }
    // ones rows for MFMA-computed softmax denominator
    {
        const int rr = 64 + (tid >> 4);
        const int cc = (tid & 15) * 4;
        short4 ones; ones.x = 0x3F80; ones.y = 0x3F80; ones.z = 0x3F80; ones.w = 0x3F80;
        *(short4*)&Vt[rr * FKP + cc] = ones;
    }
    __syncthreads();
    shortx8 Of0 = *(const shortx8*)&Vt[(64 + l16) * FKP + quad * 8];
    shortx8 Of1 = *(const shortx8*)&Vt[(64 + l16) * FKP + 32 + quad * 8];

    floatx4 OaccA[4], OaccB[4];
#pragma unroll
    for (int i = 0; i < 4; ++i) { OaccA[i] = (floatx4){0.f, 0.f, 0.f, 0.f}; OaccB[i] = (floatx4){0.f, 0.f, 0.f, 0.f}; }
    floatx4 lA = (floatx4){0.f, 0.f, 0.f, 0.f}, lB = (floatx4){0.f, 0.f, 0.f, 0.f};

    const int sr = tid >> 2, sc = (tid & 3) * 16;
    const int prowA = wave * 32 + l16, prowB = prowA + 16;
    const short* kg = kbase + (size_t)sr * NDH + sc;
    const short* vg = vbase + (size_t)sr * NS + sc;
    shortx8 pk0 = *(const shortx8*)kg, pk1 = *(const shortx8*)(kg + 8);
    shortx8 pv0 = *(const shortx8*)vg, pv1 = *(const shortx8*)(vg + 8);

    for (int t = 0; t < NTL; ++t) {
        __syncthreads();
        *(shortx8*)&Ks[sr * FKP + sc]     = pk0;
        *(shortx8*)&Ks[sr * FKP + sc + 8] = pk1;
        *(shortx8*)&Vt[sr * FKP + sc]     = pv0;
        *(shortx8*)&Vt[sr * FKP + sc + 8] = pv1;
        __syncthreads();
        if (t + 1 < NTL) {
            kg += FKT * NDH; vg += FKT;
            pk0 = *(const shortx8*)kg; pk1 = *(const shortx8*)(kg + 8);
            pv0 = *(const shortx8*)vg; pv1 = *(const shortx8*)(vg + 8);
        }

        // S^T = K Q^T for both query sets; K-fragments read once, shared
        floatx4 SA[4], SB[4];
#pragma unroll
        for (int kbk = 0; kbk < 4; ++kbk) {
            shortx8 kf0 = *(const shortx8*)&Ks[(kbk * 16 + l16) * FKP + quad * 8];
            shortx8 kf1 = *(const shortx8*)&Ks[(kbk * 16 + l16) * FKP + 32 + quad * 8];
            floatx4 sa = (floatx4){0.f, 0.f, 0.f, 0.f};
            sa = __builtin_amdgcn_mfma_f32_16x16x32_bf16(kf0, QfA0, sa, 0, 0, 0);
            sa = __builtin_amdgcn_mfma_f32_16x16x32_bf16(kf1, QfA1, sa, 0, 0, 0);
            SA[kbk] = sa;
            floatx4 sb = (floatx4){0.f, 0.f, 0.f, 0.f};
            sb = __builtin_amdgcn_mfma_f32_16x16x32_bf16(kf0, QfB0, sb, 0, 0, 0);
            sb = __builtin_amdgcn_mfma_f32_16x16x32_bf16(kf1, QfB1, sb, 0, 0, 0);
            SB[kbk] = sb;
        }
        // no-max softmax numerators (exp2 domain), RTZ pack
#pragma unroll
        for (int kbk = 0; kbk < 4; ++kbk) {
            uint2 u;
            u.x = pack_bf2_rz(exp2f(SA[kbk][0]), exp2f(SA[kbk][1]));
            u.y = pack_bf2_rz(exp2f(SA[kbk][2]), exp2f(SA[kbk][3]));
            *(uint2*)&Pl[prowA * FKP + kbk * 16 + quad * 4] = u;
            uint2 w;
            w.x = pack_bf2_rz(exp2f(SB[kbk][0]), exp2f(SB[kbk][1]));
            w.y = pack_bf2_rz(exp2f(SB[kbk][2]), exp2f(SB[kbk][3]));
            *(uint2*)&Pl[prowB * FKP + kbk * 16 + quad * 4] = w;
        }
        __asm__ __volatile__("" ::: "memory");   // P is intra-wave: no barrier needed
        shortx8 PfA0 = *(const shortx8*)&Pl[prowA * FKP + quad * 8];
        shortx8 PfA1 = *(const shortx8*)&Pl[prowA * FKP + 32 + quad * 8];
        shortx8 PfB0 = *(const shortx8*)&Pl[prowB * FKP + quad * 8];
        shortx8 PfB1 = *(const shortx8*)&Pl[prowB * FKP + 32 + quad * 8];
#pragma unroll
        for (int ct = 0; ct < 4; ++ct) {
            shortx8 vf0 = *(const shortx8*)&Vt[(ct * 16 + l16) * FKP + quad * 8];
            shortx8 vf1 = *(const shortx8*)&Vt[(ct * 16 + l16) * FKP + 32 + quad * 8];
            OaccA[ct] = __builtin_amdgcn_mfma_f32_16x16x32_bf16(PfA0, vf0, OaccA[ct], 0, 0, 0);
            OaccA[ct] = __builtin_amdgcn_mfma_f32_16x16x32_bf16(PfA1, vf1, OaccA[ct], 0, 0, 0);
            OaccB[ct] = __builtin_amdgcn_mfma_f32_16x16x32_bf16(PfB0, vf0, OaccB[ct], 0, 0, 0);
            OaccB[ct] = __builtin_amdgcn_mfma_f32_16x16x32_bf16(PfB1, vf1, OaccB[ct], 0, 0, 0);
        }
        lA = __builtin_amdgcn_mfma_f32_16x16x32_bf16(PfA0, Of0, lA, 0, 0, 0);
        lA = __builtin_amdgcn_mfma_f32_16x16x32_bf16(PfA1, Of1, lA, 0, 0, 0);
        lB = __builtin_amdgcn_mfma_f32_16x16x32_bf16(PfB0, Of0, lB, 0, 0, 0);
        lB = __builtin_amdgcn_mfma_f32_16x16x32_bf16(PfB1, Of1, lB, 0, 0, 0);
    }
    // epilogue: both sets
#pragma unroll
    for (int s2 = 0; s2 < 2; ++s2) {
        floatx4* Oacc = s2 ? OaccB : OaccA;
        floatx4 ls = s2 ? lB : lA;
        float lr[4];
#pragma unroll
        for (int i = 0; i < 4; ++i) lr[i] = __shfl(ls[i], quad * 16);
#pragma unroll
        for (int i = 0; i < 4; ++i) {
            const float inv = 1.0f / lr[i];
            const int row = q0 + wave * 32 + s2 * 16 + quad * 4 + i;
            __hip_bfloat16* op = o + ((size_t)(bb * NS + row)) * NDM + hh * NDH + l16;
            op[0]  = __float2bfloat16(Oacc[0][i] * inv);
            op[16] = __float2bfloat16(Oacc[1][i] * inv);
            op[32] = __float2bfloat16(Oacc[2][i] * inv);
            op[48] = __float2bfloat16(Oacc[3][i] * inv);
        }
    }
}

extern "C" void kernel_launch(void* const* d_in, const int* in_sizes, int n_in,
                              void* d_out, int out_size, void* d_ws, size_t ws_size,
                              hipStream_t stream) {
    const float* features = (const float*)d_in[0];
    const float* align    = (const float*)d_in[1];
    const int*   nseg     = (const int*)d_in[2];
    const float* W_in  = (const float*)d_in[3];
    const float* b_in  = (const float*)d_in[4];
    const float* ln1_s = (const float*)d_in[5];
    const float* ln1_b = (const float*)d_in[6];
    const float* Wq = (const float*)d_in[7];
    const float* Wk = (const float*)d_in[8];
    const float* Wv = (const float*)d_in[9];
    const float* Wo = (const float*)d_in[10];
    const float* ls1   = (const float*)d_in[11];
    const float* ln2_s = (const float*)d_in[12];
    const float* ln2_b = (const float*)d_in[13];
    const float* W1 = (const float*)d_in[14];
    const float* b1 = (const float*)d_in[15];
    const float* W2 = (const float*)d_in[16];
    const float* b2 = (const float*)d_in[17];
    const float* ls2   = (const float*)d_in[18];
    const float* lnf_s = (const float*)d_in[19];
    const float* lnf_b = (const float*)d_in[20];
    const float* W_out = (const float*)d_in[21];
    const float* b_out = (const float*)d_in[22];

    const size_t SZ_BSD = (size_t)NB * NS * NDM;      // 4,718,592

    // ---- workspace map: weights & index arrays FIRST, then activations ----
    float* p = (float*)d_ws;
    __hip_bfloat16* w_inT  = (__hip_bfloat16*)p;
    __hip_bfloat16* wqkvT0 = w_inT + 512 * 512;
    __hip_bfloat16* wqkvT1 = wqkvT0 + 1536 * 512;
    __hip_bfloat16* woT0   = wqkvT1 + 1536 * 512;
    __hip_bfloat16* woT1   = woT0 + 512 * 512;
    __hip_bfloat16* w1T0   = woT1 + 512 * 512;
    __hip_bfloat16* w1T1   = w1T0 + 2048 * 512;
    __hip_bfloat16* w2T0   = w1T1 + 2048 * 512;
    __hip_bfloat16* w2T1   = w2T0 + 512 * 2048;
    __hip_bfloat16* woutT  = w2T1 + 512 * 2048;
    int* glast = (int*)(woutT + 512 * 512);
    int* perm  = glast + NB * NG;
    int* qpos  = perm + NB * NS;
    float2* ropetab = (float2*)(qpos + NB * NG);       // 36864 float2
    p = (float*)(ropetab + NS * 32);

    float* featT = p; p += (size_t)NB * NT * NDIN;                      // fp32 [b][t][d]
    float* hbuf = p; p += SZ_BSD;                                       // fp32 residual
    __hip_bfloat16* ybuf = (__hip_bfloat16*)p;  p += SZ_BSD / 2;        // bf16 LN out
    __hip_bfloat16* obuf = (__hip_bfloat16*)p;  p += SZ_BSD / 2;        // bf16 attn out
    __hip_bfloat16* ubuf = (__hip_bfloat16*)p;  p += SZ_BSD * 2;        // bf16 [9216][2048]; also qh+kh
    __hip_bfloat16* xin  = (__hip_bfloat16*)p;  p += SZ_BSD / 2;        // bf16 X; also vT
    float* quer = p; p += (size_t)NB * NG * NDIN;
    __hip_bfloat16* hq = (__hip_bfloat16*)p; p += (size_t)NB * NG * NDM / 2;
    const size_t needed = (size_t)((char*)p - (char*)d_ws);
    if (ws_size < needed) return;

    __hip_bfloat16* qh = ubuf;
    __hip_bfloat16* kh = ubuf + SZ_BSD;
    __hip_bfloat16* vT = xin;

    // ---- prep ----
    prep0_k<<<144 + 4096 + 6656, 256, 0, stream>>>(ropetab, features, featT,
            W_in, Wq, Wk, Wv, Wo, W1, W2, W_out,
            w_inT, wqkvT0, wqkvT1, woT0, woT1, w1T0, w1T1, w2T0, w2T1, woutT);
    pool_k<<<NB * NG, 256, 0, stream>>>(align, featT, glast, quer);
    rank_k<<<dim3((NS + 255) / 256, NB), 256, 0, stream>>>(glast, nseg, perm, qpos);
    buildx_k<<<(NB * NS * (NDIN / 4) + 255) / 256, 256, 0, stream>>>(featT, quer, perm, xin);

    const int M = NB * NS;   // 9216
    bgemm64_k<0><<<dim3(NDM / 128, M / 64), 256, 0, stream>>>(xin, w_inT, hbuf, b_in, nullptr, nullptr, nullptr, M, NDM, NDIN);

    for (int l = 0; l < NL; ++l) {
        __hip_bfloat16* wqkvT = (l ? wqkvT1 : wqkvT0);
        __hip_bfloat16* woT   = (l ? woT1 : woT0);
        __hip_bfloat16* w1T   = (l ? w1T1 : w1T0);
        __hip_bfloat16* w2T   = (l ? w2T1 : w2T0);

        lnw_k<<<M / 4, 256, 0, stream>>>(hbuf, ybuf, ln1_s + l * NDM, ln1_b + l * NDM);
        bgemmqkv_k<<<dim3(1536 / 128, M / 128), 256, 0, stream>>>(ybuf, wqkvT, qh, kh, vT, ropetab);
        fattn_k<<<(NS / 128) * NH * NB, 256, 0, stream>>>(qh, kh, vT, obuf);
        bgemm64_k<2><<<dim3(NDM / 128, M / 64), 256, 0, stream>>>(obuf, woT, hbuf, nullptr, ls1 + l * NDM, hbuf, nullptr, M, NDM, NDM);
        lnw_k<<<M / 4, 256, 0, stream>>>(hbuf, ybuf, ln2_s + l * NDM, ln2_b + l * NDM);
        bgemmw1_k<<<dim3(NFF / 128, M / 128), 256, 0, stream>>>(ybuf, w1T, ubuf, b1 + l * NFF, M, NFF, NDM);
        bgemm64_k<2><<<dim3(NDM / 128, M / 64), 256, 0, stream>>>(ubuf, w2T, hbuf, b2 + l * NDM, ls2 + l * NDM, hbuf, nullptr, M, NDM, NFF);
    }

    lnwg_k<<<NB * NG, 64, 0, stream>>>(hbuf, hq, lnf_s, lnf_b, qpos);
    bgemm64_k<4><<<dim3(NDIN / 128, (NB * NG) / 64), 256, 0, stream>>>(hq, woutT, d_out, b_out, nullptr, nullptr, nseg, NB * NG, NDIN, NDM);
}